// Round 3
// baseline (194.835 us; speedup 1.0000x reference)
//
#include <hip/hip_runtime.h>
#include <math.h>

// HoltWintersDecomposition: x (8192, 2048) f32, sequential recurrence per row.
// 256 blocks x 32 lanes (1 wave/CU), lane = row. x stays in registers (per-lane
// float4, P/Q double-buffer, 1-tile prefetch). Outputs transposed through padded
// LDS tiles ([32][65], conflict-free scalar writes) and stored coalesced every
// 64 steps (each store instr = 8 fully-used 64B lines). Single wave per block ->
// no barriers needed. Chain: rcp + 1 Newton for the two state reciprocals.

constexpr int   T   = 2048;
constexpr int   B   = 8192;
constexpr int   RPB = 32;          // rows per block = lanes
constexpr int   TT  = 64;          // steps per tile
constexpr int   NT  = T / TT;      // 32 tiles
constexpr int   LP  = TT + 1;      // 65: LDS stride -> bank (lane+t)%32, clean
constexpr float EPS = 1e-8f;

__device__ __forceinline__ float rcp_nr(float d) {
    float r = __builtin_amdgcn_rcpf(d);
    float e = __builtin_fmaf(-d, r, 1.0f);   // e = 1 - d*r
    return __builtin_fmaf(r, e, r);          // ~1 ulp
}

__global__ __launch_bounds__(32, 1)
void hw_kernel(const float* __restrict__ x,
               const float* __restrict__ pla,
               const float* __restrict__ plg,
               float* __restrict__ out)
{
    __shared__ float lb[RPB][LP];
    __shared__ float sb[RPB][LP];
    __shared__ float yb[RPB][LP];

    const int lane = threadIdx.x;
    const int row0 = blockIdx.x * RPB;
    const int row  = row0 + lane;

    const float alpha = 1.0f / (1.0f + expf(-pla[0]));
    const float gamma = 1.0f / (1.0f + expf(-plg[0]));
    const float oma = 1.0f - alpha;
    const float omg = 1.0f - gamma;

    const float* __restrict__ xrow = x + (size_t)row * T;
    float* __restrict__ lout = out;
    float* __restrict__ sout = out + (size_t)B * T;
    float* __restrict__ yout = out + (size_t)2 * B * T;

    // store-phase lane mapping: lane i -> rows 2k+(i>>4), cols (i&15)*4
    const int sr = lane >> 4;
    const int sc = (lane & 15) << 2;

    float4 P[16], Q[16];

    auto loadT = [&](float4* R, int tile) {
        const float* p = xrow + tile * TT;
        #pragma unroll
        for (int k = 0; k < 16; ++k)
            R[k] = *reinterpret_cast<const float4*>(p + 4 * k);
    };

    float lp = 0.0f, sp = 1.0f;

    auto step = [&](float xt, int idx) {
        const float rs = rcp_nr(sp + EPS);
        const float lt = __builtin_fmaf(alpha * xt, rs, oma * lp);
        const float rl = rcp_nr(lt + EPS);
        const float st = __builtin_fmaf(gamma * xt, rl, omg * sp);
        const float yt = xt * __builtin_amdgcn_rcpf(__builtin_fmaf(lt, st, EPS));
        lb[lane][idx] = lt;
        sb[lane][idx] = st;
        yb[lane][idx] = yt;
        lp = lt; sp = st;
    };

    auto computeT = [&](const float4* R, bool first) {
        #pragma unroll
        for (int q = 0; q < 16; ++q) {
            const float4 xv = R[q];
            if (first && q == 0) {
                // t == 0: l0 = x0, s0 = 1, y0 = x0/(x0 + eps)
                const float xt = xv.x;
                lp = xt; sp = 1.0f;
                lb[lane][0] = xt;
                sb[lane][0] = 1.0f;
                yb[lane][0] = xt * __builtin_amdgcn_rcpf(xt + EPS);
                step(xv.y, 1); step(xv.z, 2); step(xv.w, 3);
            } else {
                step(xv.x, 4 * q + 0);
                step(xv.y, 4 * q + 1);
                step(xv.z, 4 * q + 2);
                step(xv.w, 4 * q + 3);
            }
        }
    };

    auto storeT = [&](int tile) {
        const size_t tb = (size_t)tile * TT + sc;
        #pragma unroll
        for (int k = 0; k < 16; ++k) {
            const int r = 2 * k + sr;
            const size_t g = (size_t)(row0 + r) * T + tb;
            float4 vl, vs, vy;
            vl.x = lb[r][sc + 0]; vl.y = lb[r][sc + 1];
            vl.z = lb[r][sc + 2]; vl.w = lb[r][sc + 3];
            vs.x = sb[r][sc + 0]; vs.y = sb[r][sc + 1];
            vs.z = sb[r][sc + 2]; vs.w = sb[r][sc + 3];
            vy.x = yb[r][sc + 0]; vy.y = yb[r][sc + 1];
            vy.z = yb[r][sc + 2]; vy.w = yb[r][sc + 3];
            *reinterpret_cast<float4*>(lout + g) = vl;
            *reinterpret_cast<float4*>(sout + g) = vs;
            *reinterpret_cast<float4*>(yout + g) = vy;
        }
    };

    // prologue: tiles 0,1 in flight; peel tile 0 (FIRST)
    loadT(P, 0);
    loadT(Q, 1);
    computeT(P, true);
    storeT(0);
    loadT(P, 2);

    // steady state: Q then P per iteration; loads 1 tile ahead of consumption
    #pragma unroll 1
    for (int c = 1; c < NT; c += 2) {
        computeT(Q, false);
        storeT(c);
        loadT(Q, (c + 2 < NT) ? c + 2 : NT - 1);
        if (c + 1 < NT) {
            computeT(P, false);
            storeT(c + 1);
            loadT(P, (c + 3 < NT) ? c + 3 : NT - 1);
        }
    }
}

extern "C" void kernel_launch(void* const* d_in, const int* in_sizes, int n_in,
                              void* d_out, int out_size, void* d_ws, size_t ws_size,
                              hipStream_t stream) {
    const float* x   = (const float*)d_in[0];
    const float* pla = (const float*)d_in[1];
    const float* plg = (const float*)d_in[2];
    float* out = (float*)d_out;

    dim3 grid(B / RPB);   // 256 blocks -> 1 per CU
    dim3 block(RPB);      // 32 lanes, single wave
    hw_kernel<<<grid, block, 0, stream>>>(x, pla, plg, out);
}